// Round 7
// baseline (9413.533 us; speedup 1.0000x reference)
//
#include <hip/hip_runtime.h>
#include <stdint.h>

#define B_  32
#define T_  1024
#define I_  512
#define H_  1024
#define C_  512
#define G4H 4096

typedef __bf16 bf16x8 __attribute__((ext_vector_type(8)));
typedef float  f32x4  __attribute__((ext_vector_type(4)));
typedef unsigned long long u64;

__device__ __forceinline__ unsigned short f2bf(float f) {
    uint32_t b = __float_as_uint(f);
    b = (b + 0x7FFFu + ((b >> 16) & 1u)) >> 16;
    return (unsigned short)b;
}
__device__ __forceinline__ float bf2f(unsigned short v) {
    return __uint_as_float(((uint32_t)v) << 16);
}
__device__ __forceinline__ float sigf(float x)   { return 1.0f / (1.0f + __expf(-x)); }
__device__ __forceinline__ float tanh_f(float x) { return 2.0f / (1.0f + __expf(-2.0f * x)) - 1.0f; }

// ---------------- fp32 -> bf16 conversion (vectorized x4) ----------------
__global__ void cvt_kernel(const float* __restrict__ src, unsigned short* __restrict__ dst, int n4) {
    int i = blockIdx.x * blockDim.x + threadIdx.x;
    if (i < n4) {
        float4 v = ((const float4*)src)[i];
        ushort4 o;
        o.x = f2bf(v.x); o.y = f2bf(v.y); o.z = f2bf(v.z); o.w = f2bf(v.w);
        ((ushort4*)dst)[i] = o;
    }
}

__global__ void bias_kernel(const float* __restrict__ a, const float* __restrict__ b, float* __restrict__ o) {
    int i = blockIdx.x * blockDim.x + threadIdx.x;
    if (i < G4H) o[i] = a[i] + b[i];
}

// agent-scope fill: leaves no stale L2 copies anywhere (proven R5 pattern)
__global__ void fill_kernel(u64* __restrict__ dst, u64 val, size_t n) {
    size_t i = (size_t)blockIdx.x * blockDim.x + threadIdx.x;
    if (i < n)
        __hip_atomic_store(dst + i, val, __ATOMIC_RELAXED, __HIP_MEMORY_SCOPE_AGENT);
}

// init for lstm_xcd: ctrl (cnt[8]=0, winner=-1), flags[256]=0, hall slot0 = 0
__global__ void init_kernel(u64* __restrict__ ctrl, u64* __restrict__ flags, u64* __restrict__ hall0) {
    int i = blockIdx.x * blockDim.x + threadIdx.x;   // grid 32x256 = 8192
    if (i < 5)
        __hip_atomic_store(ctrl + i, (i == 4) ? ~0ull : 0ull, __ATOMIC_RELAXED, __HIP_MEMORY_SCOPE_AGENT);
    if (i < 128)
        __hip_atomic_store(flags + i, 0ull, __ATOMIC_RELAXED, __HIP_MEMORY_SCOPE_AGENT);
    if (i < 8192)
        __hip_atomic_store(hall0 + i, 0ull, __ATOMIC_RELAXED, __HIP_MEMORY_SCOPE_AGENT);
}

// ---------------- x_gates GEMM: xg[t][b][4096] = x[b][t][:] @ W_ih^T ----------------
__global__ __launch_bounds__(256) void xg_gemm(
        const unsigned short* __restrict__ A,      // [b*1024+t][512] bf16
        const unsigned short* __restrict__ Bw,     // [4096][512] bf16
        unsigned short* __restrict__ out)          // [1024][32][4096] bf16
{
    __shared__ unsigned short As[128 * 64];
    __shared__ unsigned short Bs[128 * 64];
    const int tid  = threadIdx.x;
    const int lane = tid & 63, w = tid >> 6;
    const int wm = w >> 1, wn = w & 1;
    const int mbase = blockIdx.y * 128, nbase = blockIdx.x * 128;
    const int l15 = lane & 15, l4 = lane >> 4;

    f32x4 acc[4][4];
    #pragma unroll
    for (int i = 0; i < 4; i++)
        #pragma unroll
        for (int j = 0; j < 4; j++) acc[i][j] = (f32x4){0.f, 0.f, 0.f, 0.f};

    for (int kb = 0; kb < 8; kb++) {
        __syncthreads();
        #pragma unroll
        for (int i = 0; i < 4; i++) {
            int s = i * 256 + tid;
            int row = s >> 3, g = s & 7;
            int gd = g ^ (row & 7);
            int4 va = *(const int4*)(A  + (size_t)(mbase + row) * 512 + kb * 64 + g * 8);
            *(int4*)(As + row * 64 + gd * 8) = va;
            int4 vb = *(const int4*)(Bw + (size_t)(nbase + row) * 512 + kb * 64 + g * 8);
            *(int4*)(Bs + row * 64 + gd * 8) = vb;
        }
        __syncthreads();
        #pragma unroll
        for (int kk = 0; kk < 2; kk++) {
            bf16x8 af[4], bf[4];
            #pragma unroll
            for (int mt = 0; mt < 4; mt++) {
                int row = wm * 64 + mt * 16 + l15;
                int gg = (kk * 4 + l4) ^ (row & 7);
                af[mt] = *(const bf16x8*)(As + row * 64 + gg * 8);
            }
            #pragma unroll
            for (int nt = 0; nt < 4; nt++) {
                int row = wn * 64 + nt * 16 + l15;
                int gg = (kk * 4 + l4) ^ (row & 7);
                bf[nt] = *(const bf16x8*)(Bs + row * 64 + gg * 8);
            }
            #pragma unroll
            for (int mt = 0; mt < 4; mt++)
                #pragma unroll
                for (int nt = 0; nt < 4; nt++)
                    acc[mt][nt] = __builtin_amdgcn_mfma_f32_16x16x32_bf16(af[mt], bf[nt], acc[mt][nt], 0, 0, 0);
        }
    }
    #pragma unroll
    for (int mt = 0; mt < 4; mt++)
        #pragma unroll
        for (int nt = 0; nt < 4; nt++)
            #pragma unroll
            for (int r = 0; r < 4; r++) {
                int grow = mbase + wm * 64 + mt * 16 + l4 * 4 + r;
                int gcol = nbase + wn * 64 + nt * 16 + l15;
                int b = grow >> 10, t = grow & 1023;
                out[((size_t)t * B_ + b) * G4H + gcol] = f2bf(acc[mt][nt][r]);
            }
}

// ---------------- single-XCD persistent LSTM recurrence ----------------
// 256 WGs launched; the 32 on the "winner" XCD claim slots 0..31, rest exit.
// Slot owns hidden units [slot*32, +32) -> 128 gate-major cols.
// Weights W_hh live in VGPRs: wave (kw=wq>>1, cw=wq&1) holds K [kw*256,+256)
// x cols [cw*64,+64) = 32 bf16x8 frags = 128 VGPRs.
// LDS: hlds [32 b][128 granules] XOR-swizzled 64KB; scratch [4 kw][32 b][128 c]
// f32 swizzled 64KB; xstage [32 b][4 g][32 u] bf16 8KB.
// h exchange: plain stores/loads through the XCD-shared L2 (coherent within
// XCD; stale-L1 benign by replay determinism, first read flag-gated).
// Flags: 256 i32 (slot*8+wave), monotonic value t+1, agent-scope (LLC),
// signed >= compare (0xAA poison = negative = blocks). Zeroed per launch.
// hall2 (for post-GEMMs) written by a bulk agent-scope copy at kernel end.
__global__ __launch_bounds__(512, 2) void lstm_xcd(
        const unsigned short* __restrict__ whh,   // [4096][1024] bf16
        const unsigned short* __restrict__ xg,    // [1024][32][4096] bf16
        const float* __restrict__ bias,           // [4096]
        unsigned short* __restrict__ hall,        // [1025][32][1024] bf16 (slot0 zeroed)
        unsigned short* __restrict__ hall2,       // [1025][32][1024] bf16 (output copy)
        int* __restrict__ ctrl,                   // cnt[8], winner at [8]
        int* __restrict__ flags)                  // [256] i32
{
    extern __shared__ char smem[];
    unsigned short* hlds   = (unsigned short*)smem;            // 65536 B
    float*          scratch = (float*)(smem + 65536);          // 65536 B
    unsigned short* xstage = (unsigned short*)(smem + 131072); // 8192 B
    int*            s_slot = (int*)(smem + 139264);

    const int tid  = threadIdx.x;
    const int lane = tid & 63;
    const int wq   = tid >> 6;
    const int l15  = lane & 15;
    const int l4   = lane >> 4;

    // ---- claim a slot on the winner XCD ----
    if (tid == 0) {
        int myxcd;
        asm volatile("s_getreg_b32 %0, hwreg(HW_REG_XCC_ID, 0, 4)" : "=s"(myxcd));
        myxcd &= 7;
        int idx = __hip_atomic_fetch_add(&ctrl[myxcd], 1, __ATOMIC_RELAXED, __HIP_MEMORY_SCOPE_AGENT);
        if (idx == 31) {
            int e = -1;
            __hip_atomic_compare_exchange_strong(&ctrl[8], &e, myxcd,
                __ATOMIC_RELAXED, __ATOMIC_RELAXED, __HIP_MEMORY_SCOPE_AGENT);
        }
        int w;
        for (;;) {
            w = __hip_atomic_load(&ctrl[8], __ATOMIC_RELAXED, __HIP_MEMORY_SCOPE_AGENT);
            if (w != -1) break;
            __builtin_amdgcn_s_sleep(8);
        }
        *s_slot = (w == myxcd && idx < 32) ? idx : -1;
    }
    __syncthreads();
    const int slot = *s_slot;
    if (slot < 0) return;

    const int kw = wq >> 1, cw = wq & 1;

    // ---- W_hh slice -> VGPRs (32 bf16x8 frags) ----
    bf16x8 wf[8][4];
    #pragma unroll
    for (int ks = 0; ks < 8; ks++)
        #pragma unroll
        for (int nt = 0; nt < 4; nt++) {
            int c = cw * 64 + nt * 16 + l15;
            int grow = (c >> 5) * 1024 + slot * 32 + (c & 31);
            wf[ks][nt] = *(const bf16x8*)(whh + (size_t)grow * 1024 + kw * 256 + ks * 32 + l4 * 8);
        }

    // ---- pointwise constants: thread = (u, b0) and (u, b0+16) ----
    const int u  = tid & 31;
    const int b0 = tid >> 5;          // 0..15
    const int b1 = b0 + 16;
    const int U  = slot * 32 + u;
    const float bi = bias[U], bff = bias[1024 + U], bg = bias[2048 + U], bo = bias[3072 + U];
    float c0 = 0.f, c1 = 0.f;

    // ---- xg prefetch registers (one step ahead) ----
    const int id0 = wq * 128 + lane, id1 = id0 + 64;     // u64 ids in [0,1024)
    #define XG_SRC(tt, id) (const u64*)(xg + ((size_t)(tt) * B_ + ((id) >> 5)) * G4H \
                           + (((id) >> 3) & 3) * 1024 + slot * 32 + ((id) & 7) * 4)
    u64 xr0 = *XG_SRC(0, id0);
    u64 xr1 = *XG_SRC(0, id1);

    const int swl15 = l15 & 7;

    for (int t = 0; t < T_; ++t) {
        // ---- wait: wave 0 polls all 256 flags >= t (signed) ----
        if (t > 0 && wq == 0) {
            u64* fp = (u64*)flags + lane * 2;
            const int need = t;
            for (;;) {
                u64 a = __hip_atomic_load(fp,     __ATOMIC_RELAXED, __HIP_MEMORY_SCOPE_AGENT);
                u64 b = __hip_atomic_load(fp + 1, __ATOMIC_RELAXED, __HIP_MEMORY_SCOPE_AGENT);
                bool ok = ((int)(uint32_t)(a & 0xffffffffu) >= need) &&
                          ((int)(uint32_t)(a >> 32)         >= need) &&
                          ((int)(uint32_t)(b & 0xffffffffu) >= need) &&
                          ((int)(uint32_t)(b >> 32)         >= need);
                if (__all(ok)) break;
                __builtin_amdgcn_s_sleep(1);
            }
            asm volatile("" ::: "memory");
        }
        __syncthreads();   // BAR_A (also guards scratch/hlds/xstage WAR)

        // ---- stage h(t): wave wq stages k-cols [wq*128,+128) (plain L2 loads) ----
        {
            const unsigned short* hsrc = hall + (size_t)t * (B_ * H_);
            int b = lane >> 1, seg = lane & 1;
            #pragma unroll
            for (int j = 0; j < 8; j++) {
                int g = wq * 16 + seg * 8 + j;
                int4 v = *(const int4*)(hsrc + b * 1024 + g * 8);
                *(int4*)((char*)hlds + b * 2048 + ((g ^ (b & 7)) << 4)) = v;
            }
        }
        // xstage(t) from prefetched regs; prefetch xg(t+1)
        *(u64*)((char*)xstage + (size_t)id0 * 8) = xr0;
        *(u64*)((char*)xstage + (size_t)id1 * 8) = xr1;
        {
            int tn = (t + 1 < T_) ? t + 1 : T_ - 1;
            xr0 = *XG_SRC(tn, id0);
            xr1 = *XG_SRC(tn, id1);
        }
        __syncthreads();   // BAR_B: hlds + xstage ready

        // ---- MFMA: 8 k-steps x (2 m-tiles x 4 n-tiles) ----
        f32x4 acc[2][4];
        #pragma unroll
        for (int i = 0; i < 2; i++)
            #pragma unroll
            for (int j = 0; j < 4; j++) acc[i][j] = (f32x4){0.f, 0.f, 0.f, 0.f};

        #pragma unroll
        for (int ks = 0; ks < 8; ks++) {
            int g = kw * 32 + ks * 4 + l4;
            bf16x8 a0 = *(const bf16x8*)((char*)hlds + l15 * 2048        + ((g ^ swl15) << 4));
            bf16x8 a1 = *(const bf16x8*)((char*)hlds + (16 + l15) * 2048 + ((g ^ swl15) << 4));
            #pragma unroll
            for (int nt = 0; nt < 4; nt++) {
                acc[0][nt] = __builtin_amdgcn_mfma_f32_16x16x32_bf16(a0, wf[ks][nt], acc[0][nt], 0, 0, 0);
                acc[1][nt] = __builtin_amdgcn_mfma_f32_16x16x32_bf16(a1, wf[ks][nt], acc[1][nt], 0, 0, 0);
            }
        }

        // ---- partials -> scratch (swizzled, ~2-way max) ----
        #pragma unroll
        for (int mt = 0; mt < 2; mt++)
            #pragma unroll
            for (int nt = 0; nt < 4; nt++)
                #pragma unroll
                for (int r = 0; r < 4; r++) {
                    int b = mt * 16 + l4 * 4 + r;
                    int c = cw * 64 + nt * 16 + l15;
                    scratch[((kw * 32 + b) << 7) + (c ^ (((b >> 2) & 1) << 4))] = acc[mt][nt][r];
                }
        __syncthreads();   // BAR_C

        // ---- pointwise (2 units of work) + publish ----
        unsigned short* hd = hall + (size_t)(t + 1) * (B_ * H_);
        unsigned short hv0, hv1;
        {
            int sw = ((b0 >> 2) & 1) << 4;
            float pi = bi + bf2f(xstage[b0 * 128 + u]);
            float pf = bff + bf2f(xstage[b0 * 128 + 32 + u]);
            float pg = bg + bf2f(xstage[b0 * 128 + 64 + u]);
            float po = bo + bf2f(xstage[b0 * 128 + 96 + u]);
            #pragma unroll
            for (int q = 0; q < 4; q++) {
                const float* sc = scratch + ((q * 32 + b0) << 7);
                pi += sc[(u) ^ sw]; pf += sc[(32 + u) ^ sw];
                pg += sc[(64 + u) ^ sw]; po += sc[(96 + u) ^ sw];
            }
            float ig = sigf(pi), fg = sigf(pf), gg = tanh_f(pg), og = sigf(po);
            c0 = fg * c0 + ig * gg;
            hv0 = f2bf(og * tanh_f(c0));
            hd[b0 * 1024 + U] = hv0;                       // plain store -> local L2
        }
        {
            int sw = ((b1 >> 2) & 1) << 4;
            float pi = bi + bf2f(xstage[b1 * 128 + u]);
            float pf = bff + bf2f(xstage[b1 * 128 + 32 + u]);
            float pg = bg + bf2f(xstage[b1 * 128 + 64 + u]);
            float po = bo + bf2f(xstage[b1 * 128 + 96 + u]);
            #pragma unroll
            for (int q = 0; q < 4; q++) {
                const float* sc = scratch + ((q * 32 + b1) << 7);
                pi += sc[(u) ^ sw]; pf += sc[(32 + u) ^ sw];
                pg += sc[(64 + u) ^ sw]; po += sc[(96 + u) ^ sw];
            }
            float ig = sigf(pi), fg = sigf(pf), gg = tanh_f(pg), og = sigf(po);
            c1 = fg * c1 + ig * gg;
            hv1 = f2bf(og * tanh_f(c1));
            hd[b1 * 1024 + U] = hv1;
        }
        asm volatile("s_waitcnt vmcnt(0)" ::: "memory");   // wave-level: all lanes' stores done
        if (lane == 0)
            __hip_atomic_store(&flags[slot * 8 + wq], t + 1, __ATOMIC_RELAXED, __HIP_MEMORY_SCOPE_AGENT);
    }

    // ---- final: wait everyone, then bulk copy hall -> hall2 (agent scope) ----
    if (wq == 0) {
        u64* fp = (u64*)flags + lane * 2;
        for (;;) {
            u64 a = __hip_atomic_load(fp,     __ATOMIC_RELAXED, __HIP_MEMORY_SCOPE_AGENT);
            u64 b = __hip_atomic_load(fp + 1, __ATOMIC_RELAXED, __HIP_MEMORY_SCOPE_AGENT);
            bool ok = ((int)(uint32_t)(a & 0xffffffffu) >= T_) &&
                      ((int)(uint32_t)(a >> 32)         >= T_) &&
                      ((int)(uint32_t)(b & 0xffffffffu) >= T_) &&
                      ((int)(uint32_t)(b >> 32)         >= T_);
            if (__all(ok)) break;
            __builtin_amdgcn_s_sleep(1);
        }
        asm volatile("" ::: "memory");
    }
    __syncthreads();
    {
        const u64* hs64 = (const u64*)(hall + 32768);
        u64* hd64 = (u64*)(hall2 + 32768);
        size_t base = (size_t)slot * 262144;
        for (int j = tid; j < 262144; j += 512) {
            u64 v = hs64[base + j];
            __hip_atomic_store(&hd64[base + j], v, __ATOMIC_RELAXED, __HIP_MEMORY_SCOPE_AGENT);
        }
    }
}

// ---------------- fallback: proven R2 recurrence (128 WGs, LLC flags) ----------------
__global__ __launch_bounds__(512, 1) void lstm_fb(
        const unsigned short* __restrict__ whh,
        const unsigned short* __restrict__ wih,
        const unsigned short* __restrict__ xb,    // [B][T][I] bf16
        const float* __restrict__ bias,
        unsigned short* __restrict__ hall,
        unsigned int* __restrict__ flags)         // [1024][128]
{
    extern __shared__ char smem[];
    unsigned short* Wlds    = (unsigned short*)smem;
    float*          scratch = (float*)(smem + 98304);
    float*          biasl   = (float*)(smem + 98304 + 32768);
    unsigned short* hstage  = (unsigned short*)(smem + 98304 + 32768 + 128);

    const int tid  = threadIdx.x;
    const int wg   = blockIdx.x;
    const int lane = tid & 63;
    const int wq   = tid >> 6;
    const int l15  = lane & 15;
    const int l4   = lane >> 4;

    for (int s = tid; s < 32 * 192; s += 512) {
        int col = s / 192, g = s % 192;
        int grow = (col >> 3) * H_ + wg * 8 + (col & 7);
        const unsigned short* src = (g < 128) ? (whh + grow * H_ + g * 8)
                                              : (wih + grow * I_ + (g - 128) * 8);
        int4 v = *(const int4*)src;
        int gd = g ^ (col & 7);
        *(int4*)(Wlds + col * 1536 + gd * 8) = v;
    }
    if (tid < 32)
        biasl[tid] = bias[(tid >> 3) * H_ + wg * 8 + (tid & 7)];
    __syncthreads();

    float c_state = 0.0f;

    for (int t = 0; t < T_; ++t) {
        f32x4 acc[2][2];
        #pragma unroll
        for (int a = 0; a < 2; a++)
            #pragma unroll
            for (int b = 0; b < 2; b++) acc[a][b] = (f32x4){0.f, 0.f, 0.f, 0.f};

        #pragma unroll
        for (int kxs = 0; kxs < 2; kxs++) {
            int kk = wq * 64 + kxs * 32 + l4 * 8;
            bf16x8 af[2];
            #pragma unroll
            for (int mt = 0; mt < 2; mt++) {
                int bb = mt * 16 + l15;
                af[mt] = *(const bf16x8*)(xb + ((size_t)bb * T_ + t) * I_ + kk);
            }
            int gbase = 128 + (kk >> 3);
            bf16x8 bfr[2];
            #pragma unroll
            for (int nt = 0; nt < 2; nt++) {
                int col = nt * 16 + l15;
                int gg = gbase ^ (col & 7);
                bfr[nt] = *(const bf16x8*)(Wlds + col * 1536 + gg * 8);
            }
            #pragma unroll
            for (int mt = 0; mt < 2; mt++)
                #pragma unroll
                for (int nt = 0; nt < 2; nt++)
                    acc[mt][nt] = __builtin_amdgcn_mfma_f32_16x16x32_bf16(af[mt], bfr[nt], acc[mt][nt], 0, 0, 0);
        }

        if (t > 0) {
            if (tid < 128) {
                unsigned int* f = flags + (size_t)(t - 1) * 128 + tid;
                while (__hip_atomic_load(f, __ATOMIC_RELAXED, __HIP_MEMORY_SCOPE_AGENT) == 0u)
                    __builtin_amdgcn_s_sleep(1);
            }
            __syncthreads();
            asm volatile("" ::: "memory");
        }

        const unsigned short* hprev = hall + (size_t)t * (B_ * H_);
        #pragma unroll
        for (int khs = 0; khs < 4; khs++) {
            int kk = wq * 128 + khs * 32 + l4 * 8;
            bf16x8 af[2];
            #pragma unroll
            for (int mt = 0; mt < 2; mt++) {
                int bb = mt * 16 + l15;
                af[mt] = *(const bf16x8*)(hprev + bb * H_ + kk);
            }
            int gbase = kk >> 3;
            bf16x8 bfr[2];
            #pragma unroll
            for (int nt = 0; nt < 2; nt++) {
                int col = nt * 16 + l15;
                int gg = gbase ^ (col & 7);
                bfr[nt] = *(const bf16x8*)(Wlds + col * 1536 + gg * 8);
            }
            #pragma unroll
            for (int mt = 0; mt < 2; mt++)
                #pragma unroll
                for (int nt = 0; nt < 2; nt++)
                    acc[mt][nt] = __builtin_amdgcn_mfma_f32_16x16x32_bf16(af[mt], bfr[nt], acc[mt][nt], 0, 0, 0);
        }

        #pragma unroll
        for (int mt = 0; mt < 2; mt++)
            #pragma unroll
            for (int nt = 0; nt < 2; nt++)
                #pragma unroll
                for (int r = 0; r < 4; r++) {
                    int bb  = mt * 16 + l4 * 4 + r;
                    int col = nt * 16 + l15;
                    scratch[(wq * 32 + bb) * 32 + col] = acc[mt][nt][r];
                }
        __syncthreads();

        if (tid < 256) {
            int bb = tid >> 3, u = tid & 7;
            float p0 = biasl[u], p1 = biasl[8 + u], p2 = biasl[16 + u], p3 = biasl[24 + u];
            #pragma unroll
            for (int q = 0; q < 8; q++) {
                const float* sc = scratch + (q * 32 + bb) * 32;
                p0 += sc[u]; p1 += sc[8 + u]; p2 += sc[16 + u]; p3 += sc[24 + u];
            }
            float ig = sigf(p0), fg = sigf(p1), gg = tanh_f(p2), og = sigf(p3);
            c_state = fg * c_state + ig * gg;
            float h = og * tanh_f(c_state);
            hstage[bb * 8 + u] = f2bf(h);
        }
        __syncthreads();

        if (tid < 64) {
            int bb = tid >> 1, part = tid & 1;
            u64 q = *(u64*)(hstage + bb * 8 + part * 4);
            u64* dst = (u64*)(hall + ((size_t)(t + 1) * B_ + bb) * H_ + wg * 8 + part * 4);
            __hip_atomic_store(dst, q, __ATOMIC_RELAXED, __HIP_MEMORY_SCOPE_AGENT);
        }
        __syncthreads();
        if (tid == 0)
            __hip_atomic_store(flags + (size_t)t * 128 + wg, 1u,
                               __ATOMIC_RELAXED, __HIP_MEMORY_SCOPE_AGENT);
    }
}

// ---------------- output GEMMs: C[M x N] = A[M x 1024] * B[N x 1024]^T + bias ----------------
template<int PERM>
__global__ __launch_bounds__(256) void gemm_bt(
        const unsigned short* __restrict__ A,
        const unsigned short* __restrict__ Bw,
        const float* __restrict__ bias,
        float* __restrict__ out)
{
    __shared__ unsigned short As[128 * 64];
    __shared__ unsigned short Bs[128 * 64];
    const int tid  = threadIdx.x;
    const int lane = tid & 63, w = tid >> 6;
    const int wm = w >> 1, wn = w & 1;
    const int mbase = blockIdx.y * 128, nbase = blockIdx.x * 128;
    const int l15 = lane & 15, l4 = lane >> 4;

    f32x4 acc[4][4];
    #pragma unroll
    for (int i = 0; i < 4; i++)
        #pragma unroll
        for (int j = 0; j < 4; j++) acc[i][j] = (f32x4){0.f, 0.f, 0.f, 0.f};

    for (int kb = 0; kb < 16; kb++) {
        __syncthreads();
        #pragma unroll
        for (int i = 0; i < 4; i++) {
            int s = i * 256 + tid;
            int row = s >> 3, g = s & 7;
            int gd = g ^ (row & 7);
            int4 va = *(const int4*)(A  + (size_t)(mbase + row) * 1024 + kb * 64 + g * 8);
            *(int4*)(As + row * 64 + gd * 8) = va;
            int4 vb = *(const int4*)(Bw + (size_t)(nbase + row) * 1024 + kb * 64 + g * 8);
            *(int4*)(Bs + row * 64 + gd * 8) = vb;
        }
        __syncthreads();
        #pragma unroll
        for (int kk = 0; kk < 2; kk++) {
            bf16x8 af[4], bf[4];
            #pragma unroll
            for (int mt = 0; mt < 4; mt++) {
                int row = wm * 64 + mt * 16 + l15;
                int gg = (kk * 4 + l4) ^ (row & 7);
                af[mt] = *(const bf16x8*)(As + row * 64 + gg * 8);
            }
            #pragma unroll
            for (int nt = 0; nt < 4; nt++) {
                int row = wn * 64 + nt * 16 + l15;
                int gg = (kk * 4 + l4) ^ (row & 7);
                bf[nt] = *(const bf16x8*)(Bs + row * 64 + gg * 8);
            }
            #pragma unroll
            for (int mt = 0; mt < 4; mt++)
                #pragma unroll
                for (int nt = 0; nt < 4; nt++)
                    acc[mt][nt] = __builtin_amdgcn_mfma_f32_16x16x32_bf16(af[mt], bf[nt], acc[mt][nt], 0, 0, 0);
        }
    }
    #pragma unroll
    for (int mt = 0; mt < 4; mt++)
        #pragma unroll
        for (int nt = 0; nt < 4; nt++)
            #pragma unroll
            for (int r = 0; r < 4; r++) {
                int grow = mbase + wm * 64 + mt * 16 + l4 * 4 + r;
                int gcol = nbase + wn * 64 + nt * 16 + l15;
                float v = acc[mt][nt][r] + bias[gcol];
                int idx;
                if (PERM == 1) {
                    int tt = grow >> 5, bb = grow & 31;
                    idx = (bb * 1024 + tt) * 512 + gcol;
                } else {
                    idx = grow * 1024 + gcol;
                }
                out[idx] = v;
            }
}

// ---------------- host ----------------
extern "C" void kernel_launch(void* const* d_in, const int* in_sizes, int n_in,
                              void* d_out, int out_size, void* d_ws, size_t ws_size,
                              hipStream_t stream) {
    (void)in_sizes; (void)n_in; (void)out_size;
    const float* x    = (const float*)d_in[0];
    const float* Wih  = (const float*)d_in[1];
    const float* Whh  = (const float*)d_in[2];
    const float* bih  = (const float*)d_in[3];
    const float* bhh  = (const float*)d_in[4];
    const float* fcw  = (const float*)d_in[5];
    const float* fcb  = (const float*)d_in[6];
    const float* lnw  = (const float*)d_in[7];
    const float* lnb  = (const float*)d_in[8];
    float* out = (float*)d_out;

    char* ws = (char*)d_ws;
    size_t o = 0;
    unsigned short* whh_b = (unsigned short*)(ws + o); o += 8388608;
    unsigned short* wih_b = (unsigned short*)(ws + o); o += 4194304;
    unsigned short* fcw_b = (unsigned short*)(ws + o); o += 1048576;
    unsigned short* lnw_b = (unsigned short*)(ws + o); o += 2097152;
    float*          bias_c = (float*)(ws + o);         o += 16384;
    unsigned short* hall  = (unsigned short*)(ws + o); o += 67174400;   // x_b overlays this in XG path
    unsigned short* hall2 = (unsigned short*)(ws + o); o += 67174400;
    int*            ctrl  = (int*)(ws + o);            o += 64;
    int*            flagsX = (int*)(ws + o);           o += 1024;
    unsigned short* xgbuf = (unsigned short*)(ws + o); o += 268435456;
    const int use_xg = (ws_size >= o) ? 1 : 0;

    cvt_kernel<<<4096,  256, 0, stream>>>(Whh, whh_b, 4194304 / 4);
    cvt_kernel<<<2048,  256, 0, stream>>>(Wih, wih_b, 2097152 / 4);
    cvt_kernel<<<512,   256, 0, stream>>>(fcw, fcw_b, 524288 / 4);
    cvt_kernel<<<1024,  256, 0, stream>>>(lnw, lnw_b, 1048576 / 4);
    bias_kernel<<<16, 256, 0, stream>>>(bih, bhh, bias_c);

    if (use_xg) {
        unsigned short* x_b = hall;   // overlay: dead after xg_gemm
        cvt_kernel<<<16384, 256, 0, stream>>>(x, x_b, 16777216 / 4);        // [B][T][I] bf16
        xg_gemm<<<dim3(32, 256), 256, 0, stream>>>(x_b, wih_b, xgbuf);
        init_kernel<<<32, 256, 0, stream>>>((u64*)ctrl, (u64*)flagsX, (u64*)hall);

        const unsigned short* a0 = whh_b;
        const unsigned short* a1 = xgbuf;
        const float*          a2 = bias_c;
        unsigned short*       a3 = hall;
        unsigned short*       a4 = hall2;
        int*                  a5 = ctrl;
        int*                  a6 = flagsX;
        void* args[7] = { (void*)&a0, (void*)&a1, (void*)&a2, (void*)&a3,
                          (void*)&a4, (void*)&a5, (void*)&a6 };
        hipLaunchCooperativeKernel((void*)lstm_xcd, dim3(256), dim3(512), args,
                                   (unsigned)(139264 + 16), stream);

        const unsigned short* hseq = hall2 + 32768;
        gemm_bt<1><<<dim3(4, 256), 256, 0, stream>>>(hseq, fcw_b, fcb, out);
        gemm_bt<2><<<dim3(8, 256), 256, 0, stream>>>(hseq, lnw_b, lnb, out + 16777216);
    } else {
        // fallback layout reuses the tail space for x_b + flags
        unsigned short* x_b   = (unsigned short*)(ws + 82919424);            // 32MB
        unsigned int*   flags = (unsigned int*)(ws + 82919424 + 33554432);   // 512KB
        hipMemsetAsync(flags, 0, 524288, stream);
        hipMemsetAsync(hall, 0, 65536, stream);
        cvt_kernel<<<16384, 256, 0, stream>>>(x, x_b, 16777216 / 4);

        const unsigned short* a0 = whh_b;
        const unsigned short* a1 = wih_b;
        const unsigned short* a2 = x_b;
        const float*          a3 = bias_c;
        unsigned short*       a4 = hall;
        unsigned int*         a5 = flags;
        void* args[6] = { (void*)&a0, (void*)&a1, (void*)&a2, (void*)&a3, (void*)&a4, (void*)&a5 };
        hipLaunchCooperativeKernel((void*)lstm_fb, dim3(128), dim3(512), args,
                                   (unsigned)131712, stream);

        const unsigned short* hseq = hall + 32768;
        gemm_bt<1><<<dim3(4, 256), 256, 0, stream>>>(hseq, fcw_b, fcb, out);
        gemm_bt<2><<<dim3(8, 256), 256, 0, stream>>>(hseq, lnw_b, lnb, out + 16777216);
    }
}

// Round 9
// 5224.203 us; speedup vs baseline: 1.8019x; 1.8019x over previous
//
#include <hip/hip_runtime.h>
#include <stdint.h>

#define B_  32
#define T_  1024
#define I_  512
#define H_  1024
#define C_  512
#define G4H 4096
#define NWG 128

typedef __bf16 bf16x8 __attribute__((ext_vector_type(8)));
typedef float  f32x4  __attribute__((ext_vector_type(4)));
typedef unsigned long long u64;

__device__ __forceinline__ unsigned short f2bf(float f) {
    uint32_t b = __float_as_uint(f);
    b = (b + 0x7FFFu + ((b >> 16) & 1u)) >> 16;
    return (unsigned short)b;
}
__device__ __forceinline__ float sigf(float x)   { return 1.0f / (1.0f + __expf(-x)); }
__device__ __forceinline__ float tanh_f(float x) { return 2.0f / (1.0f + __expf(-2.0f * x)) - 1.0f; }

// ---------------- fp32 -> bf16 conversion (vectorized x4) ----------------
__global__ void cvt_kernel(const float* __restrict__ src, unsigned short* __restrict__ dst, int n4) {
    int i = blockIdx.x * blockDim.x + threadIdx.x;
    if (i < n4) {
        float4 v = ((const float4*)src)[i];
        ushort4 o;
        o.x = f2bf(v.x); o.y = f2bf(v.y); o.z = f2bf(v.z); o.w = f2bf(v.w);
        ((ushort4*)dst)[i] = o;
    }
}

__global__ void bias_kernel(const float* __restrict__ a, const float* __restrict__ b, float* __restrict__ o) {
    int i = blockIdx.x * blockDim.x + threadIdx.x;
    if (i < G4H) o[i] = a[i] + b[i];
}

// ---------------- persistent LSTM recurrence (R2 topology, tuned sync) ----------------
// 128 WGs x 512 threads (cooperative for co-residency; no grid.sync).
// WG wg owns hidden units [wg*8,+8) -> 32 gate cols. LDS W slice [32 cols][1536 K]
// bf16 XOR-swizzled by 16B granule (g ^ (col&7)); per-wave K split: x-K [wq*64,+64),
// h-K [wq*128,+128). x A-frags register-prefetched one step ahead (HBM off-path).
// Sync per step: producers -> per-wave publish (hstage -> lgkmcnt -> 16x8B agent
// stores -> vmcnt(0) -> LDS monotonic done-counter; last of 4 waves does ONE agent
// fetch_add on its 16-WG group counter). Consumers: 8 lanes poll 8 padded counters
// (each on own 64B line) for ==16. Two __syncthreads per step.
__global__ __launch_bounds__(512, 1) void lstm_rec(
        const unsigned short* __restrict__ whh,      // [4096][1024] bf16
        const unsigned short* __restrict__ wih,      // [4096][512]  bf16
        const unsigned short* __restrict__ xb,       // [32][1024][512] bf16 ([B][T][I])
        const float* __restrict__ bias,              // [4096] (b_ih + b_hh)
        unsigned short* __restrict__ hall,           // [1025][32][1024] bf16 (slot0 zeroed)
        unsigned int* __restrict__ counters)         // [1025][128] dwords, ctr c at t*128+c*16
{
    extern __shared__ char smem[];
    unsigned short* Wlds    = (unsigned short*)smem;                  // 98304 B
    float*          scratch = (float*)(smem + 98304);                 // 32768 B
    unsigned short* hstage  = (unsigned short*)(smem + 131072);       // 512 B
    int*            done    = (int*)(smem + 131584);                  // 4 B

    const int tid  = threadIdx.x;
    const int wg   = blockIdx.x;
    const int lane = tid & 63;
    const int wq   = tid >> 6;
    const int l15  = lane & 15;
    const int l4   = lane >> 4;

    // ---- one-time: stage W slice into LDS (swizzled)  [R2-proven] ----
    for (int s = tid; s < 32 * 192; s += 512) {
        int col = s / 192, g = s % 192;
        int grow = (col >> 3) * H_ + wg * 8 + (col & 7);
        const unsigned short* src = (g < 128) ? (whh + grow * H_ + g * 8)
                                              : (wih + grow * I_ + (g - 128) * 8);
        int4 v = *(const int4*)src;
        int gd = g ^ (col & 7);
        *(int4*)(Wlds + col * 1536 + gd * 8) = v;
    }
    float bs0 = 0.f, bs1 = 0.f, bs2 = 0.f, bs3 = 0.f;
    if (tid < 256) {
        int u = tid & 7;
        bs0 = bias[0 * H_ + wg * 8 + u];
        bs1 = bias[1 * H_ + wg * 8 + u];
        bs2 = bias[2 * H_ + wg * 8 + u];
        bs3 = bias[3 * H_ + wg * 8 + u];
    }
    if (tid == 0) *done = 0;
    __syncthreads();

    float c_state = 0.0f;

    // ---- prime x(0) register frags: [kxs][mt] ----
    bf16x8 xr[2][2];
    #pragma unroll
    for (int kxs = 0; kxs < 2; kxs++) {
        int kk = wq * 64 + kxs * 32 + l4 * 8;
        #pragma unroll
        for (int mt = 0; mt < 2; mt++) {
            int bb = mt * 16 + l15;
            xr[kxs][mt] = *(const bf16x8*)(xb + ((size_t)bb * T_ + 0) * I_ + kk);
        }
    }

    for (int t = 0; t < T_; ++t) {
        f32x4 acc[2][2];
        #pragma unroll
        for (int a = 0; a < 2; a++)
            #pragma unroll
            for (int b = 0; b < 2; b++) acc[a][b] = (f32x4){0.f, 0.f, 0.f, 0.f};

        // ---- x-part from prefetched registers ----
        #pragma unroll
        for (int kxs = 0; kxs < 2; kxs++) {
            int kk = wq * 64 + kxs * 32 + l4 * 8;
            int gbase = 128 + (kk >> 3);
            bf16x8 bfr[2];
            #pragma unroll
            for (int nt = 0; nt < 2; nt++) {
                int col = nt * 16 + l15;
                int gg = gbase ^ (col & 7);
                bfr[nt] = *(const bf16x8*)(Wlds + col * 1536 + gg * 8);
            }
            #pragma unroll
            for (int mt = 0; mt < 2; mt++)
                #pragma unroll
                for (int nt = 0; nt < 2; nt++)
                    acc[mt][nt] = __builtin_amdgcn_mfma_f32_16x16x32_bf16(xr[kxs][mt], bfr[nt], acc[mt][nt], 0, 0, 0);
        }

        // ---- issue x(t+1) loads (fill during wait/h/pointwise) ----
        {
            int tn = (t + 1 < T_) ? t + 1 : T_ - 1;
            #pragma unroll
            for (int kxs = 0; kxs < 2; kxs++) {
                int kk = wq * 64 + kxs * 32 + l4 * 8;
                #pragma unroll
                for (int mt = 0; mt < 2; mt++) {
                    int bb = mt * 16 + l15;
                    xr[kxs][mt] = *(const bf16x8*)(xb + ((size_t)bb * T_ + tn) * I_ + kk);
                }
            }
        }

        // ---- wait for h(t): 8 lanes poll 8 aggregated counters (==16 each) ----
        if (t > 0) {
            if (tid < 8) {
                const unsigned int* cp = counters + (size_t)t * 128 + tid * 16;
                while (__hip_atomic_load(cp, __ATOMIC_RELAXED, __HIP_MEMORY_SCOPE_AGENT) < 16u)
                    __builtin_amdgcn_s_sleep(1);
            }
            __syncthreads();   // bar_W: h slot t fully published
            asm volatile("" ::: "memory");
        }

        // ---- h-part (plain cached loads)  [R2-proven] ----
        const unsigned short* hprev = hall + (size_t)t * (B_ * H_);
        #pragma unroll
        for (int khs = 0; khs < 4; khs++) {
            int kk = wq * 128 + khs * 32 + l4 * 8;
            bf16x8 af[2];
            #pragma unroll
            for (int mt = 0; mt < 2; mt++) {
                int bb = mt * 16 + l15;
                af[mt] = *(const bf16x8*)(hprev + bb * H_ + kk);
            }
            int gbase = kk >> 3;
            bf16x8 bfr[2];
            #pragma unroll
            for (int nt = 0; nt < 2; nt++) {
                int col = nt * 16 + l15;
                int gg = gbase ^ (col & 7);
                bfr[nt] = *(const bf16x8*)(Wlds + col * 1536 + gg * 8);
            }
            #pragma unroll
            for (int mt = 0; mt < 2; mt++)
                #pragma unroll
                for (int nt = 0; nt < 2; nt++)
                    acc[mt][nt] = __builtin_amdgcn_mfma_f32_16x16x32_bf16(af[mt], bfr[nt], acc[mt][nt], 0, 0, 0);
        }

        // ---- partials -> per-wave scratch region (swizzled plain writes, <=2-way) ----
        float* myscr = scratch + wq * 1024;
        #pragma unroll
        for (int mt = 0; mt < 2; mt++)
            #pragma unroll
            for (int nt = 0; nt < 2; nt++)
                #pragma unroll
                for (int r = 0; r < 4; r++) {
                    int bb  = mt * 16 + l4 * 4 + r;
                    int col = nt * 16 + l15;
                    myscr[bb * 32 + (col ^ ((bb & 7) << 2))] = acc[mt][nt][r];
                }
        __syncthreads();   // bar_B: scratch(t) complete
        // WAR safety: scratch(t+1)/hstage(t+1) writes are gated by bar_W(t+1),
        // which requires counters[t+1]==16, which requires own WG's pointwise
        // to have finished reading scratch(t). Single buffer is safe.

        // ---- pointwise + per-wave staggered publish (waves 0-3) ----
        if (tid < 256) {
            int bb = tid >> 3, u = tid & 7;
            int sw = (bb & 7) << 2;
            float p0 = bs0, p1 = bs1, p2 = bs2, p3 = bs3;
            const float* base = scratch + bb * 32;
            #pragma unroll
            for (int q = 0; q < 8; q++) {
                const float* sc = base + q * 1024;
                p0 += sc[(u)      ^ sw];
                p1 += sc[(8 + u)  ^ sw];
                p2 += sc[(16 + u) ^ sw];
                p3 += sc[(24 + u) ^ sw];
            }
            float ig = sigf(p0), fg = sigf(p1), gg = tanh_f(p2), og = sigf(p3);
            c_state = fg * c_state + ig * gg;
            float h = og * tanh_f(c_state);
            hstage[bb * 8 + u] = f2bf(h);            // wave-private 128B chunk
            asm volatile("s_waitcnt lgkmcnt(0)" ::: "memory");

            int w = wq, i = lane;
            if (i < 16) {
                int pb = w * 8 + (i >> 1), part = i & 1;
                u64 q = *(const u64*)(hstage + pb * 8 + part * 4);
                u64* dst = (u64*)(hall + ((size_t)(t + 1) * B_ + pb) * H_ + wg * 8 + part * 4);
                __hip_atomic_store(dst, q, __ATOMIC_RELAXED, __HIP_MEMORY_SCOPE_AGENT);
            }
            asm volatile("s_waitcnt vmcnt(0)" ::: "memory");   // this wave's h at LLC
            if (i == 0) {
                int old = __hip_atomic_fetch_add(done, 1, __ATOMIC_RELAXED, __HIP_MEMORY_SCOPE_WORKGROUP);
                if (old == t * 4 + 3) {
                    // last pointwise wave of this WG at step t: all 4 waves drained
                    __hip_atomic_fetch_add(counters + (size_t)(t + 1) * 128 + (wg >> 4) * 16, 1u,
                                           __ATOMIC_RELAXED, __HIP_MEMORY_SCOPE_AGENT);
                }
            }
        }
    }
}

// ---------------- output GEMMs: C[M x N] = A[M x 1024] * B[N x 1024]^T + bias ----------------
template<int PERM>
__global__ __launch_bounds__(256) void gemm_bt(
        const unsigned short* __restrict__ A,
        const unsigned short* __restrict__ Bw,
        const float* __restrict__ bias,
        float* __restrict__ out)
{
    __shared__ unsigned short As[128 * 64];
    __shared__ unsigned short Bs[128 * 64];
    const int tid  = threadIdx.x;
    const int lane = tid & 63, w = tid >> 6;
    const int wm = w >> 1, wn = w & 1;
    const int mbase = blockIdx.y * 128, nbase = blockIdx.x * 128;
    const int l15 = lane & 15, l4 = lane >> 4;

    f32x4 acc[4][4];
    #pragma unroll
    for (int i = 0; i < 4; i++)
        #pragma unroll
        for (int j = 0; j < 4; j++) acc[i][j] = (f32x4){0.f, 0.f, 0.f, 0.f};

    for (int kb = 0; kb < 16; kb++) {
        __syncthreads();
        #pragma unroll
        for (int i = 0; i < 4; i++) {
            int s = i * 256 + tid;
            int row = s >> 3, g = s & 7;
            int gd = g ^ (row & 7);
            int4 va = *(const int4*)(A  + (size_t)(mbase + row) * 1024 + kb * 64 + g * 8);
            *(int4*)(As + row * 64 + gd * 8) = va;
            int4 vb = *(const int4*)(Bw + (size_t)(nbase + row) * 1024 + kb * 64 + g * 8);
            *(int4*)(Bs + row * 64 + gd * 8) = vb;
        }
        __syncthreads();
        #pragma unroll
        for (int kk = 0; kk < 2; kk++) {
            bf16x8 af[4], bf[4];
            #pragma unroll
            for (int mt = 0; mt < 4; mt++) {
                int row = wm * 64 + mt * 16 + l15;
                int gg = (kk * 4 + l4) ^ (row & 7);
                af[mt] = *(const bf16x8*)(As + row * 64 + gg * 8);
            }
            #pragma unroll
            for (int nt = 0; nt < 4; nt++) {
                int row = wn * 64 + nt * 16 + l15;
                int gg = (kk * 4 + l4) ^ (row & 7);
                bf[nt] = *(const bf16x8*)(Bs + row * 64 + gg * 8);
            }
            #pragma unroll
            for (int mt = 0; mt < 4; mt++)
                #pragma unroll
                for (int nt = 0; nt < 4; nt++)
                    acc[mt][nt] = __builtin_amdgcn_mfma_f32_16x16x32_bf16(af[mt], bf[nt], acc[mt][nt], 0, 0, 0);
        }
    }
    #pragma unroll
    for (int mt = 0; mt < 4; mt++)
        #pragma unroll
        for (int nt = 0; nt < 4; nt++)
            #pragma unroll
            for (int r = 0; r < 4; r++) {
                int grow = mbase + wm * 64 + mt * 16 + l4 * 4 + r;
                int gcol = nbase + wn * 64 + nt * 16 + l15;
                float v = acc[mt][nt][r] + bias[gcol];
                int idx;
                if (PERM == 1) {
                    int tt = grow >> 5, bb = grow & 31;
                    idx = (bb * 1024 + tt) * 512 + gcol;
                } else {
                    idx = grow * 1024 + gcol;
                }
                out[idx] = v;
            }
}

// ---------------- host ----------------
extern "C" void kernel_launch(void* const* d_in, const int* in_sizes, int n_in,
                              void* d_out, int out_size, void* d_ws, size_t ws_size,
                              hipStream_t stream) {
    (void)in_sizes; (void)n_in; (void)out_size; (void)ws_size;
    const float* x    = (const float*)d_in[0];
    const float* Wih  = (const float*)d_in[1];
    const float* Whh  = (const float*)d_in[2];
    const float* bih  = (const float*)d_in[3];
    const float* bhh  = (const float*)d_in[4];
    const float* fcw  = (const float*)d_in[5];
    const float* fcb  = (const float*)d_in[6];
    const float* lnw  = (const float*)d_in[7];
    const float* lnb  = (const float*)d_in[8];
    float* out = (float*)d_out;

    char* ws = (char*)d_ws;
    size_t o = 0;
    unsigned short* whh_b = (unsigned short*)(ws + o); o += 8388608;   // [4096][1024]
    unsigned short* wih_b = (unsigned short*)(ws + o); o += 4194304;   // [4096][512]
    unsigned short* fcw_b = (unsigned short*)(ws + o); o += 1048576;   // [512][1024]
    unsigned short* lnw_b = (unsigned short*)(ws + o); o += 2097152;   // [1024][1024]
    unsigned short* x_b   = (unsigned short*)(ws + o); o += 33554432;  // [B][T][I] bf16
    float*          bias_c = (float*)(ws + o);         o += 16384;     // [4096]
    unsigned short* hall  = (unsigned short*)(ws + o); o += 67174400;  // [1025][32][1024]
    unsigned int*   counters = (unsigned int*)(ws + o); o += 524800;   // [1025][128] dw

    hipMemsetAsync(counters, 0, 524800, stream);
    hipMemsetAsync(hall, 0, 65536, stream);      // h slot 0 = zeros

    cvt_kernel<<<4096,  256, 0, stream>>>(Whh, whh_b, 4194304 / 4);
    cvt_kernel<<<2048,  256, 0, stream>>>(Wih, wih_b, 2097152 / 4);
    cvt_kernel<<<512,   256, 0, stream>>>(fcw, fcw_b, 524288 / 4);
    cvt_kernel<<<1024,  256, 0, stream>>>(lnw, lnw_b, 1048576 / 4);
    cvt_kernel<<<16384, 256, 0, stream>>>(x,   x_b,   16777216 / 4);
    bias_kernel<<<16, 256, 0, stream>>>(bih, bhh, bias_c);

    const unsigned short* a0 = whh_b;
    const unsigned short* a1 = wih_b;
    const unsigned short* a2 = x_b;
    const float*          a3 = bias_c;
    unsigned short*       a4 = hall;
    unsigned int*         a5 = counters;
    void* args[6] = { (void*)&a0, (void*)&a1, (void*)&a2, (void*)&a3, (void*)&a4, (void*)&a5 };
    hipLaunchCooperativeKernel((void*)lstm_rec, dim3(NWG), dim3(512), args,
                               (unsigned)131600, stream);

    const unsigned short* hseq = hall + 32768;  // slot 1 = h at t=0
    gemm_bt<1><<<dim3(4, 256), 256, 0, stream>>>(hseq, fcw_b, fcb, out);
    gemm_bt<2><<<dim3(8, 256), 256, 0, stream>>>(hseq, lnw_b, lnb, out + 16777216);
}

// Round 10
// 4446.531 us; speedup vs baseline: 2.1171x; 1.1749x over previous
//
#include <hip/hip_runtime.h>
#include <stdint.h>

#define B_  32
#define T_  1024
#define I_  512
#define H_  1024
#define C_  512
#define G4H 4096
#define NWG 128

typedef __bf16 bf16x8 __attribute__((ext_vector_type(8)));
typedef float  f32x4  __attribute__((ext_vector_type(4)));
typedef unsigned long long u64;

__device__ __forceinline__ unsigned short f2bf(float f) {
    uint32_t b = __float_as_uint(f);
    b = (b + 0x7FFFu + ((b >> 16) & 1u)) >> 16;
    return (unsigned short)b;
}
__device__ __forceinline__ float sigf(float x)   { return 1.0f / (1.0f + __expf(-x)); }
__device__ __forceinline__ float tanh_f(float x) { return 2.0f / (1.0f + __expf(-2.0f * x)) - 1.0f; }

// ---------------- fp32 -> bf16 conversion (vectorized x4) ----------------
__global__ void cvt_kernel(const float* __restrict__ src, unsigned short* __restrict__ dst, int n4) {
    int i = blockIdx.x * blockDim.x + threadIdx.x;
    if (i < n4) {
        float4 v = ((const float4*)src)[i];
        ushort4 o;
        o.x = f2bf(v.x); o.y = f2bf(v.y); o.z = f2bf(v.z); o.w = f2bf(v.w);
        ((ushort4*)dst)[i] = o;
    }
}

// x: [B][T][I] fp32 -> [T][B][I] bf16 (per-step slice contiguous 32KB)
__global__ void cvt_x_kernel(const float* __restrict__ src, unsigned short* __restrict__ dst) {
    int i4 = blockIdx.x * blockDim.x + threadIdx.x;       // over B*T*I/4
    int b   = i4 / (T_ * I_ / 4);
    int rem = i4 % (T_ * I_ / 4);
    int t   = rem / (I_ / 4);
    int c4  = rem % (I_ / 4);
    float4 v = ((const float4*)src)[i4];
    ushort4 o;
    o.x = f2bf(v.x); o.y = f2bf(v.y); o.z = f2bf(v.z); o.w = f2bf(v.w);
    ((ushort4*)dst)[(t * B_ + b) * (I_ / 4) + c4] = o;
}

__global__ void bias_kernel(const float* __restrict__ a, const float* __restrict__ b, float* __restrict__ o) {
    int i = blockIdx.x * blockDim.x + threadIdx.x;
    if (i < G4H) o[i] = a[i] + b[i];
}

// ---------------- persistent LSTM recurrence (R2 skeleton, line-padded flags) ----------------
// 128 WGs x 512 threads (cooperative for co-residency; NO grid.sync).
// WG wg owns hidden units [wg*8, wg*8+8) -> 32 gate cols.
// LDS W slice [32 cols][1536 K] bf16, XOR-swizzled by 16B granule (g ^ (col&7)).
// K split per wave wq: h-K [wq*128,+128) (4 mfma k-steps), x-K [wq*64,+64) (2).
// Cross-WG h exchange: bulk publish (tid<64, 8B agent stores) -> barrier ->
// single flag store by tid==0. EACH FLAG OWNS A FULL 64B LINE (stride 16 dw):
// producers never false-share; each flag line is polled by exactly one lane
// per WG (128 pollers/line with s_sleep(1)) -> no line congestion.
__global__ __launch_bounds__(512, 1) void lstm_rec(
        const unsigned short* __restrict__ whh,   // [4096][1024] bf16
        const unsigned short* __restrict__ wih,   // [4096][512]  bf16
        const unsigned short* __restrict__ xb,    // [1024][32][512] bf16
        const float* __restrict__ bias,           // [4096] (b_ih + b_hh)
        unsigned short* __restrict__ hall,        // [1025][32][1024] bf16 (slot 0 pre-zeroed)
        unsigned int* __restrict__ flags)         // [1024][128][16] dw (pre-zeroed, 64B/flag)
{
    extern __shared__ char smem[];
    unsigned short* Wlds    = (unsigned short*)smem;                     // 98304 B
    float*          scratch = (float*)(smem + 98304);                    // 32768 B
    unsigned short* hstage  = (unsigned short*)(smem + 98304 + 32768);   // 512 B

    const int tid  = threadIdx.x;
    const int wg   = blockIdx.x;
    const int lane = tid & 63;
    const int wq   = tid >> 6;          // wave id 0..7
    const int l15  = lane & 15;
    const int l4   = lane >> 4;

    // ---- one-time: stage W slice into LDS (swizzled) ----
    for (int s = tid; s < 32 * 192; s += 512) {
        int col = s / 192, g = s % 192;
        int grow = (col >> 3) * H_ + wg * 8 + (col & 7);   // global gate row
        const unsigned short* src = (g < 128) ? (whh + grow * H_ + g * 8)
                                              : (wih + grow * I_ + (g - 128) * 8);
        int4 v = *(const int4*)src;
        int gd = g ^ (col & 7);
        *(int4*)(Wlds + col * 1536 + gd * 8) = v;
    }
    float bs0 = 0.f, bs1 = 0.f, bs2 = 0.f, bs3 = 0.f;
    if (tid < 256) {
        int u = tid & 7;
        bs0 = bias[0 * H_ + wg * 8 + u];
        bs1 = bias[1 * H_ + wg * 8 + u];
        bs2 = bias[2 * H_ + wg * 8 + u];
        bs3 = bias[3 * H_ + wg * 8 + u];
    }
    __syncthreads();

    float c_state = 0.0f;

    for (int t = 0; t < T_; ++t) {
        f32x4 acc[2][2];
        #pragma unroll
        for (int a = 0; a < 2; a++)
            #pragma unroll
            for (int b = 0; b < 2; b++) acc[a][b] = (f32x4){0.f, 0.f, 0.f, 0.f};

        // ---- x-part first: no dependency on h_t, hides producer latency ----
        #pragma unroll
        for (int kxs = 0; kxs < 2; kxs++) {
            int kk = wq * 64 + kxs * 32 + l4 * 8;      // x-K local [0,512)
            bf16x8 af[2];
            #pragma unroll
            for (int mt = 0; mt < 2; mt++) {
                int bb = mt * 16 + l15;
                af[mt] = *(const bf16x8*)(xb + ((size_t)t * B_ + bb) * I_ + kk);
            }
            int gbase = 128 + (kk >> 3);               // x granules at 128..191
            bf16x8 bfr[2];
            #pragma unroll
            for (int nt = 0; nt < 2; nt++) {
                int col = nt * 16 + l15;
                int gg = gbase ^ (col & 7);
                bfr[nt] = *(const bf16x8*)(Wlds + col * 1536 + gg * 8);
            }
            #pragma unroll
            for (int mt = 0; mt < 2; mt++)
                #pragma unroll
                for (int nt = 0; nt < 2; nt++)
                    acc[mt][nt] = __builtin_amdgcn_mfma_f32_16x16x32_bf16(af[mt], bfr[nt], acc[mt][nt], 0, 0, 0);
        }

        // ---- wait for all h_t slices: one lane per flag LINE ----
        if (t > 0) {
            if (tid < NWG) {
                const unsigned int* f = flags + ((size_t)(t - 1) * NWG + tid) * 16;
                while (__hip_atomic_load(f, __ATOMIC_RELAXED, __HIP_MEMORY_SCOPE_AGENT) == 0u)
                    __builtin_amdgcn_s_sleep(1);
            }
            __syncthreads();
            asm volatile("" ::: "memory");
        }

        // ---- h-part ----
        const unsigned short* hprev = hall + (size_t)t * (B_ * H_);
        #pragma unroll
        for (int khs = 0; khs < 4; khs++) {
            int kk = wq * 128 + khs * 32 + l4 * 8;     // h-K [0,1024)
            bf16x8 af[2];
            #pragma unroll
            for (int mt = 0; mt < 2; mt++) {
                int bb = mt * 16 + l15;
                af[mt] = *(const bf16x8*)(hprev + bb * H_ + kk);
            }
            int gbase = kk >> 3;
            bf16x8 bfr[2];
            #pragma unroll
            for (int nt = 0; nt < 2; nt++) {
                int col = nt * 16 + l15;
                int gg = gbase ^ (col & 7);
                bfr[nt] = *(const bf16x8*)(Wlds + col * 1536 + gg * 8);
            }
            #pragma unroll
            for (int mt = 0; mt < 2; mt++)
                #pragma unroll
                for (int nt = 0; nt < 2; nt++)
                    acc[mt][nt] = __builtin_amdgcn_mfma_f32_16x16x32_bf16(af[mt], bfr[nt], acc[mt][nt], 0, 0, 0);
        }

        // ---- partial results -> LDS scratch (bank-swizzled writes, <=2-way) ----
        float* myscr = scratch + wq * 1024;
        #pragma unroll
        for (int mt = 0; mt < 2; mt++)
            #pragma unroll
            for (int nt = 0; nt < 2; nt++)
                #pragma unroll
                for (int r = 0; r < 4; r++) {
                    int bb  = mt * 16 + l4 * 4 + r;       // batch (D row)
                    int col = nt * 16 + l15;              // gate col (D col)
                    myscr[bb * 32 + (col ^ ((bb & 7) << 2))] = acc[mt][nt][r];
                }
        __syncthreads();

        // ---- pointwise LSTM cell: 256 threads = 32 batches x 8 units ----
        if (tid < 256) {
            int bb = tid >> 3, u = tid & 7;
            int sw = (bb & 7) << 2;
            float p0 = bs0, p1 = bs1, p2 = bs2, p3 = bs3;
            const float* base = scratch + bb * 32;
            #pragma unroll
            for (int q = 0; q < 8; q++) {
                const float* sc = base + q * 1024;
                p0 += sc[(u)      ^ sw];
                p1 += sc[(8 + u)  ^ sw];
                p2 += sc[(16 + u) ^ sw];
                p3 += sc[(24 + u) ^ sw];
            }
            float ig = sigf(p0), fg = sigf(p1), gg = tanh_f(p2), og = sigf(p3);
            c_state = fg * c_state + ig * gg;
            float h = og * tanh_f(c_state);
            hstage[bb * 8 + u] = f2bf(h);
        }
        __syncthreads();

        // ---- publish h slice: L2-bypass 8B stores -> LLC-coherent ----
        if (tid < 64) {
            int bb = tid >> 1, part = tid & 1;
            u64 q = *(u64*)(hstage + bb * 8 + part * 4);
            u64* dst = (u64*)(hall + ((size_t)(t + 1) * B_ + bb) * H_ + wg * 8 + part * 4);
            __hip_atomic_store(dst, q, __ATOMIC_RELAXED, __HIP_MEMORY_SCOPE_AGENT);
        }
        __syncthreads();   // drains vmcnt per thread -> all h stores at LLC
        if (tid == 0)
            __hip_atomic_store(flags + ((size_t)t * NWG + wg) * 16, 1u,
                               __ATOMIC_RELAXED, __HIP_MEMORY_SCOPE_AGENT);
    }
}

// ---------------- output GEMMs: C[M x N] = A[M x 1024] * B[N x 1024]^T + bias ----------------
template<int PERM>
__global__ __launch_bounds__(256) void gemm_bt(
        const unsigned short* __restrict__ A,
        const unsigned short* __restrict__ Bw,
        const float* __restrict__ bias,
        float* __restrict__ out)
{
    __shared__ unsigned short As[128 * 64];
    __shared__ unsigned short Bs[128 * 64];
    const int tid  = threadIdx.x;
    const int lane = tid & 63, w = tid >> 6;
    const int wm = w >> 1, wn = w & 1;
    const int mbase = blockIdx.y * 128, nbase = blockIdx.x * 128;
    const int l15 = lane & 15, l4 = lane >> 4;

    f32x4 acc[4][4];
    #pragma unroll
    for (int i = 0; i < 4; i++)
        #pragma unroll
        for (int j = 0; j < 4; j++) acc[i][j] = (f32x4){0.f, 0.f, 0.f, 0.f};

    for (int kb = 0; kb < 16; kb++) {
        __syncthreads();
        #pragma unroll
        for (int i = 0; i < 4; i++) {
            int s = i * 256 + tid;
            int row = s >> 3, g = s & 7;
            int gd = g ^ (row & 7);
            int4 va = *(const int4*)(A  + (size_t)(mbase + row) * 1024 + kb * 64 + g * 8);
            *(int4*)(As + row * 64 + gd * 8) = va;
            int4 vb = *(const int4*)(Bw + (size_t)(nbase + row) * 1024 + kb * 64 + g * 8);
            *(int4*)(Bs + row * 64 + gd * 8) = vb;
        }
        __syncthreads();
        #pragma unroll
        for (int kk = 0; kk < 2; kk++) {
            bf16x8 af[4], bf[4];
            #pragma unroll
            for (int mt = 0; mt < 4; mt++) {
                int row = wm * 64 + mt * 16 + l15;
                int gg = (kk * 4 + l4) ^ (row & 7);
                af[mt] = *(const bf16x8*)(As + row * 64 + gg * 8);
            }
            #pragma unroll
            for (int nt = 0; nt < 4; nt++) {
                int row = wn * 64 + nt * 16 + l15;
                int gg = (kk * 4 + l4) ^ (row & 7);
                bf[nt] = *(const bf16x8*)(Bs + row * 64 + gg * 8);
            }
            #pragma unroll
            for (int mt = 0; mt < 4; mt++)
                #pragma unroll
                for (int nt = 0; nt < 4; nt++)
                    acc[mt][nt] = __builtin_amdgcn_mfma_f32_16x16x32_bf16(af[mt], bf[nt], acc[mt][nt], 0, 0, 0);
        }
    }
    #pragma unroll
    for (int mt = 0; mt < 4; mt++)
        #pragma unroll
        for (int nt = 0; nt < 4; nt++)
            #pragma unroll
            for (int r = 0; r < 4; r++) {
                int grow = mbase + wm * 64 + mt * 16 + l4 * 4 + r;
                int gcol = nbase + wn * 64 + nt * 16 + l15;
                float v = acc[mt][nt][r] + bias[gcol];
                int idx;
                if (PERM == 1) {
                    int tt = grow >> 5, bb = grow & 31;
                    idx = (bb * 1024 + tt) * 512 + gcol;
                } else {
                    idx = grow * 1024 + gcol;
                }
                out[idx] = v;
            }
}

// ---------------- host ----------------
extern "C" void kernel_launch(void* const* d_in, const int* in_sizes, int n_in,
                              void* d_out, int out_size, void* d_ws, size_t ws_size,
                              hipStream_t stream) {
    (void)in_sizes; (void)n_in; (void)out_size; (void)ws_size;
    const float* x    = (const float*)d_in[0];
    const float* Wih  = (const float*)d_in[1];
    const float* Whh  = (const float*)d_in[2];
    const float* bih  = (const float*)d_in[3];
    const float* bhh  = (const float*)d_in[4];
    const float* fcw  = (const float*)d_in[5];
    const float* fcb  = (const float*)d_in[6];
    const float* lnw  = (const float*)d_in[7];
    const float* lnb  = (const float*)d_in[8];
    float* out = (float*)d_out;

    char* ws = (char*)d_ws;
    size_t o = 0;
    unsigned short* whh_b = (unsigned short*)(ws + o); o += 8388608;   // [4096][1024]
    unsigned short* wih_b = (unsigned short*)(ws + o); o += 4194304;   // [4096][512]
    unsigned short* fcw_b = (unsigned short*)(ws + o); o += 1048576;   // [512][1024]
    unsigned short* lnw_b = (unsigned short*)(ws + o); o += 2097152;   // [1024][1024]
    unsigned short* x_b   = (unsigned short*)(ws + o); o += 33554432;  // [1024][32][512]
    float*          bias_c = (float*)(ws + o);         o += 16384;     // [4096]
    unsigned short* hall  = (unsigned short*)(ws + o); o += 67174400;  // [1025][32][1024]
    unsigned int*   flags = (unsigned int*)(ws + o);   o += 8388608;   // [1024][128][16] dw

    hipMemsetAsync(flags, 0, 8388608, stream);
    hipMemsetAsync(hall, 0, 65536, stream);      // h slot 0 = zeros

    cvt_kernel<<<4096,  256, 0, stream>>>(Whh, whh_b, 4194304 / 4);
    cvt_kernel<<<2048,  256, 0, stream>>>(Wih, wih_b, 2097152 / 4);
    cvt_kernel<<<512,   256, 0, stream>>>(fcw, fcw_b, 524288 / 4);
    cvt_kernel<<<1024,  256, 0, stream>>>(lnw, lnw_b, 1048576 / 4);
    cvt_x_kernel<<<16384, 256, 0, stream>>>(x, x_b);
    bias_kernel<<<16, 256, 0, stream>>>(bih, bhh, bias_c);

    const unsigned short* a0 = whh_b;
    const unsigned short* a1 = wih_b;
    const unsigned short* a2 = x_b;
    const float*          a3 = bias_c;
    unsigned short*       a4 = hall;
    unsigned int*         a5 = flags;
    void* args[6] = { (void*)&a0, (void*)&a1, (void*)&a2, (void*)&a3, (void*)&a4, (void*)&a5 };
    hipLaunchCooperativeKernel((void*)lstm_rec, dim3(NWG), dim3(512), args,
                               (unsigned)(98304 + 32768 + 512), stream);

    const unsigned short* hseq = hall + 32768;  // slot 1 = h at t=0
    gemm_bt<1><<<dim3(4, 256), 256, 0, stream>>>(hseq, fcw_b, fcb, out);
    gemm_bt<2><<<dim3(8, 256), 256, 0, stream>>>(hseq, lnw_b, lnb, out + 16777216);
}

// Round 11
// 4403.471 us; speedup vs baseline: 2.1378x; 1.0098x over previous
//
#include <hip/hip_runtime.h>
#include <stdint.h>

#define B_  32
#define T_  1024
#define I_  512
#define H_  1024
#define C_  512
#define G4H 4096
#define NWG 128

typedef __bf16 bf16x8 __attribute__((ext_vector_type(8)));
typedef float  f32x4  __attribute__((ext_vector_type(4)));
typedef unsigned long long u64;

__device__ __forceinline__ unsigned short f2bf(float f) {
    uint32_t b = __float_as_uint(f);
    b = (b + 0x7FFFu + ((b >> 16) & 1u)) >> 16;
    return (unsigned short)b;
}
__device__ __forceinline__ float sigf(float x)   { return 1.0f / (1.0f + __expf(-x)); }
__device__ __forceinline__ float tanh_f(float x) { return 2.0f / (1.0f + __expf(-2.0f * x)) - 1.0f; }

// ---------------- fp32 -> bf16 conversion (vectorized x4) ----------------
__global__ void cvt_kernel(const float* __restrict__ src, unsigned short* __restrict__ dst, int n4) {
    int i = blockIdx.x * blockDim.x + threadIdx.x;
    if (i < n4) {
        float4 v = ((const float4*)src)[i];
        ushort4 o;
        o.x = f2bf(v.x); o.y = f2bf(v.y); o.z = f2bf(v.z); o.w = f2bf(v.w);
        ((ushort4*)dst)[i] = o;
    }
}

// x: [B][T][I] fp32 -> [T][B][I] bf16 (per-step slice contiguous 32KB)
__global__ void cvt_x_kernel(const float* __restrict__ src, unsigned short* __restrict__ dst) {
    int i4 = blockIdx.x * blockDim.x + threadIdx.x;       // over B*T*I/4
    int b   = i4 / (T_ * I_ / 4);
    int rem = i4 % (T_ * I_ / 4);
    int t   = rem / (I_ / 4);
    int c4  = rem % (I_ / 4);
    float4 v = ((const float4*)src)[i4];
    ushort4 o;
    o.x = f2bf(v.x); o.y = f2bf(v.y); o.z = f2bf(v.z); o.w = f2bf(v.w);
    ((ushort4*)dst)[(t * B_ + b) * (I_ / 4) + c4] = o;
}

__global__ void bias_kernel(const float* __restrict__ a, const float* __restrict__ b, float* __restrict__ o) {
    int i = blockIdx.x * blockDim.x + threadIdx.x;
    if (i < G4H) o[i] = a[i] + b[i];
}

// ---------------- persistent LSTM recurrence (1 barrier/step, per-wave dataflow) ----------------
// 128 WGs x 512 threads (cooperative for co-residency; NO grid.sync).
// WG wg owns hidden units [wg*8,+8) -> 32 gate cols.
// LDS: W_hh slice [32 cols][1024 K] bf16 XOR-swizzled (g ^ (col&7)) 64KB;
//      scratch [2 parity][8 waves][32 b][32 c] f32 64KB; hstage [32][8] 512B; done ctr.
// W_ih x-frags live in 16 VGPRs/thread (4 x bf16x8). K split/wave: x [wq*64,+64),
// h [wq*128,+128).
// WAIT (per-wave, no barrier): wave wq needs h units [wq*128,+128) = producers
// [wq*16,+16); lanes<16 poll those 16 line-padded flags, then proceed.
// PUBLISH (per-wave, staggered): pointwise wave w (w<4) computes batches
// [w*8,+8), stages h in wave-private hstage slice, lgkmcnt -> 16x8B agent
// stores -> vmcnt(0) -> LDS done++; 4th wave sets per-WG padded flag
// (value 1 at [t][wg], monotonic compare old==t*4+3, no reset).
// ONE __syncthreads per step (scratch complete). Scratch parity double-buffer
// makes WAR airtight: writes to parity p at t+2 occur after bar(t+1), which
// happens-after pointwise(t) reads of parity p.
__global__ __launch_bounds__(512, 1) void lstm_rec(
        const unsigned short* __restrict__ whh,   // [4096][1024] bf16
        const unsigned short* __restrict__ wih,   // [4096][512]  bf16
        const unsigned short* __restrict__ xb,    // [1024][32][512] bf16
        const float* __restrict__ bias,           // [4096] (b_ih + b_hh)
        unsigned short* __restrict__ hall,        // [1025][32][1024] bf16 (slot 0 pre-zeroed)
        unsigned int* __restrict__ flags)         // [1024][128][16] dw (pre-zeroed, 64B/flag)
{
    extern __shared__ char smem[];
    unsigned short* Wlds    = (unsigned short*)smem;                 // 65536 B
    float*          scratch = (float*)(smem + 65536);                // 65536 B (2 x 8192 f32)
    unsigned short* hstage  = (unsigned short*)(smem + 131072);      // 512 B
    int*            done    = (int*)(smem + 131584);                 // 4 B

    const int tid  = threadIdx.x;
    const int wg   = blockIdx.x;
    const int lane = tid & 63;
    const int wq   = tid >> 6;          // wave id 0..7
    const int l15  = lane & 15;
    const int l4   = lane >> 4;

    // ---- one-time: stage W_hh slice into LDS (swizzled) ----
    for (int s = tid; s < 32 * 128; s += 512) {
        int col = s >> 7, g = s & 127;
        int grow = (col >> 3) * H_ + wg * 8 + (col & 7);   // global gate row
        int4 v = *(const int4*)(whh + (size_t)grow * H_ + g * 8);
        *(int4*)(Wlds + col * 1024 + (g ^ (col & 7)) * 8) = v;
    }
    // ---- W_ih B-frags -> registers (this wave's x-K slice, 2 col-tiles) ----
    bf16x8 wfx[2][2];
    #pragma unroll
    for (int kxs = 0; kxs < 2; kxs++)
        #pragma unroll
        for (int nt = 0; nt < 2; nt++) {
            int col = nt * 16 + l15;
            int grow = (col >> 3) * H_ + wg * 8 + (col & 7);
            int kk = wq * 64 + kxs * 32 + l4 * 8;
            wfx[kxs][nt] = *(const bf16x8*)(wih + (size_t)grow * I_ + kk);
        }
    float bs0 = 0.f, bs1 = 0.f, bs2 = 0.f, bs3 = 0.f;
    if (tid < 256) {
        int u = tid & 7;
        bs0 = bias[0 * H_ + wg * 8 + u];
        bs1 = bias[1 * H_ + wg * 8 + u];
        bs2 = bias[2 * H_ + wg * 8 + u];
        bs3 = bias[3 * H_ + wg * 8 + u];
    }
    if (tid == 0) *done = 0;
    __syncthreads();

    float c_state = 0.0f;

    for (int t = 0; t < T_; ++t) {
        f32x4 acc[2][2];
        #pragma unroll
        for (int a = 0; a < 2; a++)
            #pragma unroll
            for (int b = 0; b < 2; b++) acc[a][b] = (f32x4){0.f, 0.f, 0.f, 0.f};

        // ---- x-part first: no h dependency; overlaps flag propagation ----
        #pragma unroll
        for (int kxs = 0; kxs < 2; kxs++) {
            int kk = wq * 64 + kxs * 32 + l4 * 8;
            bf16x8 af[2];
            #pragma unroll
            for (int mt = 0; mt < 2; mt++) {
                int bb = mt * 16 + l15;
                af[mt] = *(const bf16x8*)(xb + ((size_t)t * B_ + bb) * I_ + kk);
            }
            #pragma unroll
            for (int mt = 0; mt < 2; mt++)
                #pragma unroll
                for (int nt = 0; nt < 2; nt++)
                    acc[mt][nt] = __builtin_amdgcn_mfma_f32_16x16x32_bf16(af[mt], wfx[kxs][nt], acc[mt][nt], 0, 0, 0);
        }

        // ---- per-wave wait: this wave's 16 producer flags (padded lines) ----
        if (t > 0) {
            if (lane < 16) {
                const unsigned int* f = flags + ((size_t)(t - 1) * NWG + wq * 16 + lane) * 16;
                while (__hip_atomic_load(f, __ATOMIC_RELAXED, __HIP_MEMORY_SCOPE_AGENT) == 0u)
                    __builtin_amdgcn_s_sleep(1);
            }
            asm volatile("" ::: "memory");
        }

        // ---- h-part (plain cached loads of this wave's K slice) ----
        const unsigned short* hprev = hall + (size_t)t * (B_ * H_);
        #pragma unroll
        for (int khs = 0; khs < 4; khs++) {
            int kk = wq * 128 + khs * 32 + l4 * 8;
            bf16x8 af[2];
            #pragma unroll
            for (int mt = 0; mt < 2; mt++) {
                int bb = mt * 16 + l15;
                af[mt] = *(const bf16x8*)(hprev + bb * H_ + kk);
            }
            int gbase = kk >> 3;            // [0,128)
            bf16x8 bfr[2];
            #pragma unroll
            for (int nt = 0; nt < 2; nt++) {
                int col = nt * 16 + l15;
                int gg = gbase ^ (col & 7);
                bfr[nt] = *(const bf16x8*)(Wlds + col * 1024 + gg * 8);
            }
            #pragma unroll
            for (int mt = 0; mt < 2; mt++)
                #pragma unroll
                for (int nt = 0; nt < 2; nt++)
                    acc[mt][nt] = __builtin_amdgcn_mfma_f32_16x16x32_bf16(af[mt], bfr[nt], acc[mt][nt], 0, 0, 0);
        }

        // ---- partials -> parity scratch (swizzled plain writes, <=2-way) ----
        float* myscr = scratch + (t & 1) * 8192 + wq * 1024;
        #pragma unroll
        for (int mt = 0; mt < 2; mt++)
            #pragma unroll
            for (int nt = 0; nt < 2; nt++)
                #pragma unroll
                for (int r = 0; r < 4; r++) {
                    int bb  = mt * 16 + l4 * 4 + r;
                    int col = nt * 16 + l15;
                    myscr[bb * 32 + (col ^ ((bb & 7) << 2))] = acc[mt][nt][r];
                }
        __syncthreads();   // the ONLY barrier per step: scratch(t) complete

        // ---- pointwise + per-wave staggered publish (waves 0-3); 4-7 run ahead ----
        if (tid < 256) {
            int bb = tid >> 3, u = tid & 7;
            int sw = (bb & 7) << 2;
            float p0 = bs0, p1 = bs1, p2 = bs2, p3 = bs3;
            const float* base = scratch + (t & 1) * 8192 + bb * 32;
            #pragma unroll
            for (int q = 0; q < 8; q++) {
                const float* sc = base + q * 1024;
                p0 += sc[(u)      ^ sw];
                p1 += sc[(8 + u)  ^ sw];
                p2 += sc[(16 + u) ^ sw];
                p3 += sc[(24 + u) ^ sw];
            }
            float ig = sigf(p0), fg = sigf(p1), gg = tanh_f(p2), og = sigf(p3);
            c_state = fg * c_state + ig * gg;
            float h = og * tanh_f(c_state);
            hstage[bb * 8 + u] = f2bf(h);            // wave-private 128B slice
            asm volatile("s_waitcnt lgkmcnt(0)" ::: "memory");

            if (lane < 16) {
                int pb = wq * 8 + (lane >> 1), part = lane & 1;
                u64 q = *(const u64*)(hstage + pb * 8 + part * 4);
                u64* dst = (u64*)(hall + ((size_t)(t + 1) * B_ + pb) * H_ + wg * 8 + part * 4);
                __hip_atomic_store(dst, q, __ATOMIC_RELAXED, __HIP_MEMORY_SCOPE_AGENT);
            }
            asm volatile("s_waitcnt vmcnt(0)" ::: "memory");   // this wave's h at LLC
            if (lane == 0) {
                int old = __hip_atomic_fetch_add(done, 1, __ATOMIC_RELAXED, __HIP_MEMORY_SCOPE_WORKGROUP);
                if (old == t * 4 + 3)   // last of this WG's 4 pointwise waves at step t
                    __hip_atomic_store(flags + ((size_t)t * NWG + wg) * 16, 1u,
                                       __ATOMIC_RELAXED, __HIP_MEMORY_SCOPE_AGENT);
            }
        }
    }
}

// ---------------- output GEMMs: C[M x N] = A[M x 1024] * B[N x 1024]^T + bias ----------------
template<int PERM>
__global__ __launch_bounds__(256) void gemm_bt(
        const unsigned short* __restrict__ A,
        const unsigned short* __restrict__ Bw,
        const float* __restrict__ bias,
        float* __restrict__ out)
{
    __shared__ unsigned short As[128 * 64];
    __shared__ unsigned short Bs[128 * 64];
    const int tid  = threadIdx.x;
    const int lane = tid & 63, w = tid >> 6;
    const int wm = w >> 1, wn = w & 1;
    const int mbase = blockIdx.y * 128, nbase = blockIdx.x * 128;
    const int l15 = lane & 15, l4 = lane >> 4;

    f32x4 acc[4][4];
    #pragma unroll
    for (int i = 0; i < 4; i++)
        #pragma unroll
        for (int j = 0; j < 4; j++) acc[i][j] = (f32x4){0.f, 0.f, 0.f, 0.f};

    for (int kb = 0; kb < 16; kb++) {
        __syncthreads();
        #pragma unroll
        for (int i = 0; i < 4; i++) {
            int s = i * 256 + tid;
            int row = s >> 3, g = s & 7;
            int gd = g ^ (row & 7);
            int4 va = *(const int4*)(A  + (size_t)(mbase + row) * 1024 + kb * 64 + g * 8);
            *(int4*)(As + row * 64 + gd * 8) = va;
            int4 vb = *(const int4*)(Bw + (size_t)(nbase + row) * 1024 + kb * 64 + g * 8);
            *(int4*)(Bs + row * 64 + gd * 8) = vb;
        }
        __syncthreads();
        #pragma unroll
        for (int kk = 0; kk < 2; kk++) {
            bf16x8 af[4], bf[4];
            #pragma unroll
            for (int mt = 0; mt < 4; mt++) {
                int row = wm * 64 + mt * 16 + l15;
                int gg = (kk * 4 + l4) ^ (row & 7);
                af[mt] = *(const bf16x8*)(As + row * 64 + gg * 8);
            }
            #pragma unroll
            for (int nt = 0; nt < 4; nt++) {
                int row = wn * 64 + nt * 16 + l15;
                int gg = (kk * 4 + l4) ^ (row & 7);
                bf[nt] = *(const bf16x8*)(Bs + row * 64 + gg * 8);
            }
            #pragma unroll
            for (int mt = 0; mt < 4; mt++)
                #pragma unroll
                for (int nt = 0; nt < 4; nt++)
                    acc[mt][nt] = __builtin_amdgcn_mfma_f32_16x16x32_bf16(af[mt], bf[nt], acc[mt][nt], 0, 0, 0);
        }
    }
    #pragma unroll
    for (int mt = 0; mt < 4; mt++)
        #pragma unroll
        for (int nt = 0; nt < 4; nt++)
            #pragma unroll
            for (int r = 0; r < 4; r++) {
                int grow = mbase + wm * 64 + mt * 16 + l4 * 4 + r;
                int gcol = nbase + wn * 64 + nt * 16 + l15;
                float v = acc[mt][nt][r] + bias[gcol];
                int idx;
                if (PERM == 1) {
                    int tt = grow >> 5, bb = grow & 31;
                    idx = (bb * 1024 + tt) * 512 + gcol;
                } else {
                    idx = grow * 1024 + gcol;
                }
                out[idx] = v;
            }
}

// ---------------- host ----------------
extern "C" void kernel_launch(void* const* d_in, const int* in_sizes, int n_in,
                              void* d_out, int out_size, void* d_ws, size_t ws_size,
                              hipStream_t stream) {
    (void)in_sizes; (void)n_in; (void)out_size; (void)ws_size;
    const float* x    = (const float*)d_in[0];
    const float* Wih  = (const float*)d_in[1];
    const float* Whh  = (const float*)d_in[2];
    const float* bih  = (const float*)d_in[3];
    const float* bhh  = (const float*)d_in[4];
    const float* fcw  = (const float*)d_in[5];
    const float* fcb  = (const float*)d_in[6];
    const float* lnw  = (const float*)d_in[7];
    const float* lnb  = (const float*)d_in[8];
    float* out = (float*)d_out;

    char* ws = (char*)d_ws;
    size_t o = 0;
    unsigned short* whh_b = (unsigned short*)(ws + o); o += 8388608;   // [4096][1024]
    unsigned short* wih_b = (unsigned short*)(ws + o); o += 4194304;   // [4096][512]
    unsigned short* fcw_b = (unsigned short*)(ws + o); o += 1048576;   // [512][1024]
    unsigned short* lnw_b = (unsigned short*)(ws + o); o += 2097152;   // [1024][1024]
    unsigned short* x_b   = (unsigned short*)(ws + o); o += 33554432;  // [1024][32][512]
    float*          bias_c = (float*)(ws + o);         o += 16384;     // [4096]
    unsigned short* hall  = (unsigned short*)(ws + o); o += 67174400;  // [1025][32][1024]
    unsigned int*   flags = (unsigned int*)(ws + o);   o += 8388608;   // [1024][128][16] dw

    hipMemsetAsync(flags, 0, 8388608, stream);
    hipMemsetAsync(hall, 0, 65536, stream);      // h slot 0 = zeros

    cvt_kernel<<<4096,  256, 0, stream>>>(Whh, whh_b, 4194304 / 4);
    cvt_kernel<<<2048,  256, 0, stream>>>(Wih, wih_b, 2097152 / 4);
    cvt_kernel<<<512,   256, 0, stream>>>(fcw, fcw_b, 524288 / 4);
    cvt_kernel<<<1024,  256, 0, stream>>>(lnw, lnw_b, 1048576 / 4);
    cvt_x_kernel<<<16384, 256, 0, stream>>>(x, x_b);
    bias_kernel<<<16, 256, 0, stream>>>(bih, bhh, bias_c);

    const unsigned short* a0 = whh_b;
    const unsigned short* a1 = wih_b;
    const unsigned short* a2 = x_b;
    const float*          a3 = bias_c;
    unsigned short*       a4 = hall;
    unsigned int*         a5 = flags;
    void* args[6] = { (void*)&a0, (void*)&a1, (void*)&a2, (void*)&a3, (void*)&a4, (void*)&a5 };
    hipLaunchCooperativeKernel((void*)lstm_rec, dim3(NWG), dim3(512), args,
                               (unsigned)131600, stream);

    const unsigned short* hseq = hall + 32768;  // slot 1 = h at t=0
    gemm_bt<1><<<dim3(4, 256), 256, 0, stream>>>(hseq, fcw_b, fcb, out);
    gemm_bt<2><<<dim3(8, 256), 256, 0, stream>>>(hseq, lnw_b, lnb, out + 16777216);
}